// Round 15
// baseline (1856.030 us; speedup 1.0000x reference)
//
#include <hip/hip_runtime.h>
#include <math.h>

#define T_SEQ 120
#define BATCH 256
#define HID   512
#define G3    1536            // 3*HID
#define TS    (T_SEQ*HID)     // 61440
#define KGATE 122880          // T_SEQ*2*HID
#define FSTRIDE 16            // flag stride (ints) -> one flag per 64B line

typedef __attribute__((ext_vector_type(8))) short bf16x8;
typedef __attribute__((ext_vector_type(4))) float f32x4;

__device__ __forceinline__ unsigned short f2bf(float f) {
    union { float f; unsigned u; } x; x.f = f;
    unsigned r = x.u + 0x7fffu + ((x.u >> 16) & 1u);   // RNE
    return (unsigned short)(r >> 16);
}
__device__ __forceinline__ float bf2f(unsigned short u) {
    union { unsigned u; float f; } x; x.u = ((unsigned)u) << 16; return x.f;
}
__device__ __forceinline__ float sigm_fast(float x) {
    return 1.f / (1.f + __expf(-x));
}
__device__ __forceinline__ float tanh_fast(float x) {
    float e = __expf(2.f * x);
    return 1.f - 2.f / (e + 1.f);
}

// ---------------------------------------------------------------------------
// One prep kernel: weight casts + bias combos + flag/rolecnt init.
//  [0, T1):   Whh0 f32->bf16
//  [T1, T2):  Wcat1 = [Whh1 | Wih1] f32->bf16
//  [T2, T3):  bcomb0 / bc1 bias combos
//  [T3, T4):  flags = -1, rolecnt = 0   (re-inited every call: replay-safe)
// ---------------------------------------------------------------------------
#define P_T1 786432
#define P_T2 (P_T1 + 1572864)
#define P_T3 (P_T2 + 1536)
#define P_T4 (P_T3 + 4224)

__global__ void prep(const float* __restrict__ Whh0f, const float* __restrict__ Whh1f,
                     const float* __restrict__ Wih1f,
                     const float* __restrict__ bih0, const float* __restrict__ bhh0,
                     const float* __restrict__ bih1, const float* __restrict__ bhh1,
                     unsigned short* __restrict__ Whh0bf,
                     unsigned short* __restrict__ Wcat1bf,
                     float* __restrict__ bcomb0, float* __restrict__ bc1,
                     int* __restrict__ flags, int* __restrict__ rolecnt)
{
    int idx = blockIdx.x * 256 + threadIdx.x;
    if (idx < P_T1) {
        Whh0bf[idx] = f2bf(Whh0f[idx]);
    } else if (idx < P_T2) {
        int i = idx - P_T1;
        int row = i >> 10, c = i & 1023;
        float v = (c < 512) ? Whh1f[row * 512 + c] : Wih1f[row * 512 + (c - 512)];
        Wcat1bf[i] = f2bf(v);
    } else if (idx < P_T3) {
        int n = idx - P_T2;
        bcomb0[n] = bih0[n] + (n < 1024 ? bhh0[n] : 0.f);
        bc1[n]    = bih1[n] + (n < 1024 ? bhh1[n] : 0.f);
    } else if (idx < P_T4) {
        int k = idx - P_T3;
        if (k < 4096) flags[k] = -1;
        else          rolecnt[k - 4096] = 0;
    }
}

// ---------------------------------------------------------------------------
// XCD-partitioned persistent recurrence: r14 PROVEN kernel, unchanged.
// Each physical XCD (HW_REG_XCC_ID) owns batches [xcd*32, xcd*32+32).
// 32 resident blocks/XCD claim roles via atomicAdd: 0-15 layer0 j-blocks,
// 16-31 layer1. gx input GEMM fused into layer-0 (poll shadow, f32).
// h state IS the bf16 out buffer (fresh address every step). Data: plain
// stores + vmcnt(0); flags: AGENT atomics. ~13.6us/step = measured
// mechanism-independent inter-CU visibility floor (r8-r14).
// ---------------------------------------------------------------------------
__device__ __forceinline__ bool wait16(const int* __restrict__ fb, int thr, int lane)
{
    const int* ap = fb + (lane & 15) * FSTRIDE;
    float x0 = (float)lane, x1 = x0 + 1.f, x2 = x0 + 2.f, x3 = x0 + 3.f;
    for (int it = 0; it < 300000; ++it) {
        int v = __hip_atomic_load(ap, __ATOMIC_RELAXED, __HIP_MEMORY_SCOPE_AGENT);
        if (__all(v >= thr)) {
            asm volatile("" :: "v"(x0), "v"(x1), "v"(x2), "v"(x3));
            return true;
        }
        #pragma unroll
        for (int q = 0; q < 12; q++) {
            x0 = __builtin_fmaf(x0, 1.000001f, 1e-7f);
            x1 = __builtin_fmaf(x1, 1.000001f, 1e-7f);
            x2 = __builtin_fmaf(x2, 1.000001f, 1e-7f);
            x3 = __builtin_fmaf(x3, 1.000001f, 1e-7f);
        }
    }
    asm volatile("" :: "v"(x0), "v"(x1), "v"(x2), "v"(x3));
    return false;   // hang guard: terminate (wrong) rather than hang
}

__global__ __launch_bounds__(256) void gru_xcd(
    const float* __restrict__ X_lag,                 // [120][256][32] f32
    const float* __restrict__ X_cov,                 // [120][256][32] f32
    const float* __restrict__ Wih0,                  // [1536][64] f32
    const unsigned short* __restrict__ Whh0,         // [1536][512] bf16
    const unsigned short* __restrict__ Wcat1,        // [1536][1024] bf16
    const float* __restrict__ bhh0,
    const float* __restrict__ bcomb0,                // b_ih0 + b_hh0(r,z)
    const float* __restrict__ bc1,
    const float* __restrict__ bhh1,
    unsigned short* __restrict__ out0,               // [256][120][512] bf16
    unsigned short* __restrict__ out1,               // [256][120][512] bf16
    int* __restrict__ flags,                         // [2][8][16] x FSTRIDE
    int* __restrict__ rolecnt)                       // [8] (x16 pad)
{
    __shared__ unsigned short wlds[96 * 520];        // ~97.5 KiB (hh weights)
    __shared__ float wih[96 * 68];                   // ~25.5 KiB (L0 ih weights)
    __shared__ int role_s;

    int xcd;
    asm("s_getreg_b32 %0, hwreg(20, 0, 32)" : "=s"(xcd));   // HW_REG_XCC_ID
    xcd &= 7;
    if (threadIdx.x == 0) role_s = atomicAdd(&rolecnt[xcd * 16], 1);
    __syncthreads();
    const int role = role_s;
    if (role >= 32) return;

    const int layer = role >> 4;
    const int jb    = role & 15;
    const int j0    = jb * 32;
    const int tid   = threadIdx.x;
    const int w     = tid >> 6, lane = tid & 63;
    const int l15   = lane & 15, l4 = lane >> 4;
    const int jt    = w & 1, bt = w >> 1;
    const int jloc  = jt * 16 + l15;                 // 0..31
    const int j     = j0 + jloc;
    const int bloc0 = bt * 16;                       // 0 or 16
    const int bg0   = xcd * 32;                      // global batch base

    // stage hh-part weights (96 rows x 512) into LDS, padded stride 520
    {
        const unsigned short* Wsrc = layer ? Wcat1 : Whh0;
        const int wstr = layer ? 1024 : 512;
        for (int c = tid; c < 96 * 64; c += 256) {
            int lr = c >> 6, ck = c & 63;
            int grow = (lr >> 5) * 512 + j0 + (lr & 31);
            bf16x8 v = *(const bf16x8*)(Wsrc + (size_t)grow * wstr + ck * 8);
            *(bf16x8*)&wlds[lr * 520 + ck * 8] = v;
        }
    }
    // L0 only: stage ih weights (96 rows x 64 f32), padded stride 68
    if (!layer) {
        for (int c = tid; c < 96 * 16; c += 256) {
            int row = c >> 4, q = c & 15;
            int grow = (row >> 5) * 512 + j0 + (row & 31);
            float4 v = *(const float4*)(Wih0 + (size_t)grow * 64 + q * 4);
            *(float4*)&wih[row * 68 + q * 4] = v;
        }
    }
    float bn_, br_ = 0.f, bz_ = 0.f, bnx_ = 0.f;
    if (layer) { br_ = bc1[j]; bz_ = bc1[512 + j]; bnx_ = bc1[1024 + j]; bn_ = bhh1[1024 + j]; }
    else       { br_ = bcomb0[j]; bz_ = bcomb0[512 + j]; bnx_ = bcomb0[1024 + j]; bn_ = bhh0[1024 + j]; }
    float carry[4] = {0.f, 0.f, 0.f, 0.f};

    const int* f0b = flags + (0 * 8 + xcd) * 16 * FSTRIDE;
    const int* f1b = flags + (1 * 8 + xcd) * 16 * FSTRIDE;
    int* myf = flags + ((layer * 8 + xcd) * 16 + jb) * FSTRIDE;
    __syncthreads();                                 // weights staged

    if (!layer) {
        // ============================ layer 0 ============================
        for (int t = 0; t < T_SEQ; t++) {
            // fused gx = x_t @ Wih0^T  (f32, no h dependency -> before wait)
            float dr[4] = {}, dz[4] = {}, dn[4] = {};
            #pragma unroll
            for (int kc = 0; kc < 16; kc++) {
                float4 w0 = *(const float4*)&wih[(0 * 32 + jloc) * 68 + kc * 4];
                float4 w1 = *(const float4*)&wih[(1 * 32 + jloc) * 68 + kc * 4];
                float4 w2 = *(const float4*)&wih[(2 * 32 + jloc) * 68 + kc * 4];
                #pragma unroll
                for (int rr = 0; rr < 4; rr++) {
                    int b = bg0 + bloc0 + 4 * l4 + rr;
                    const float* xr = (kc < 8)
                        ? X_lag + ((size_t)t * 256 + b) * 32 + kc * 4
                        : X_cov + ((size_t)t * 256 + b) * 32 + (kc - 8) * 4;
                    float4 xv = *(const float4*)xr;
                    dr[rr] += xv.x * w0.x + xv.y * w0.y + xv.z * w0.z + xv.w * w0.w;
                    dz[rr] += xv.x * w1.x + xv.y * w1.y + xv.z * w1.z + xv.w * w1.w;
                    dn[rr] += xv.x * w2.x + xv.y * w2.y + xv.z * w2.z + xv.w * w2.w;
                }
            }

            if (!wait16(f0b, t - 1, lane)) break;    // all h0(t-1) published

            f32x4 a0 = {0,0,0,0}, a1 = {0,0,0,0}, a2 = {0,0,0,0};
            if (t > 0) {
                bf16x8 Areg[16];
                #pragma unroll
                for (int ks = 0; ks < 16; ks++)
                    Areg[ks] = *(const bf16x8*)(out0 + ((size_t)(bg0 + bloc0 + l15) * T_SEQ + (t - 1)) * 512 + ks * 32 + 8 * l4);
                #pragma unroll
                for (int ks = 0; ks < 16; ks++) {
                    const int ko = ks * 32 + 8 * l4;
                    bf16x8 B0 = *(const bf16x8*)&wlds[(0 * 32 + jloc) * 520 + ko];
                    bf16x8 B1 = *(const bf16x8*)&wlds[(1 * 32 + jloc) * 520 + ko];
                    bf16x8 B2 = *(const bf16x8*)&wlds[(2 * 32 + jloc) * 520 + ko];
                    a0 = __builtin_amdgcn_mfma_f32_16x16x32_bf16(Areg[ks], B0, a0, 0, 0, 0);
                    a1 = __builtin_amdgcn_mfma_f32_16x16x32_bf16(Areg[ks], B1, a1, 0, 0, 0);
                    a2 = __builtin_amdgcn_mfma_f32_16x16x32_bf16(Areg[ks], B2, a2, 0, 0, 0);
                }
            }
            #pragma unroll
            for (int rr = 0; rr < 4; rr++) {
                int b = bg0 + bloc0 + 4 * l4 + rr;
                float r = sigm_fast(dr[rr] + br_ + a0[rr]);
                float z = sigm_fast(dz[rr] + bz_ + a1[rr]);
                float n = tanh_fast(dn[rr] + bnx_ + r * (a2[rr] + bn_));
                float h = (1.f - z) * n + z * carry[rr];
                carry[rr] = h;
                out0[((size_t)b * T_SEQ + t) * 512 + j] = f2bf(h);
            }
            asm volatile("s_waitcnt vmcnt(0)" ::: "memory");  // stores in L2
            __syncthreads();
            if (tid == 0)
                __hip_atomic_store(myf, t, __ATOMIC_RELAXED, __HIP_MEMORY_SCOPE_AGENT);
        }
    } else {
        // ============================ layer 1 ============================
        for (int t = 0; t < T_SEQ; t++) {
            f32x4 a0 = {0,0,0,0}, a1 = {0,0,0,0}, a2 = {0,0,0,0}, a3 = {0,0,0,0};
            // hh-part first: only needs own-layer flags >= t-1
            if (!wait16(f1b, t - 1, lane)) break;
            if (t > 0) {
                bf16x8 Areg[16];
                #pragma unroll
                for (int ks = 0; ks < 16; ks++)
                    Areg[ks] = *(const bf16x8*)(out1 + ((size_t)(bg0 + bloc0 + l15) * T_SEQ + (t - 1)) * 512 + ks * 32 + 8 * l4);
                #pragma unroll
                for (int ks = 0; ks < 16; ks++) {
                    const int ko = ks * 32 + 8 * l4;
                    bf16x8 B0 = *(const bf16x8*)&wlds[(0 * 32 + jloc) * 520 + ko];
                    bf16x8 B1 = *(const bf16x8*)&wlds[(1 * 32 + jloc) * 520 + ko];
                    bf16x8 B2 = *(const bf16x8*)&wlds[(2 * 32 + jloc) * 520 + ko];
                    a0 = __builtin_amdgcn_mfma_f32_16x16x32_bf16(Areg[ks], B0, a0, 0, 0, 0);
                    a1 = __builtin_amdgcn_mfma_f32_16x16x32_bf16(Areg[ks], B1, a1, 0, 0, 0);
                    a2 = __builtin_amdgcn_mfma_f32_16x16x32_bf16(Areg[ks], B2, a2, 0, 0, 0);
                }
            }
            // x-part: needs layer0 flags >= t
            if (!wait16(f0b, t, lane)) break;
            {
                bf16x8 Areg[16];
                #pragma unroll
                for (int ks = 0; ks < 16; ks++)
                    Areg[ks] = *(const bf16x8*)(out0 + ((size_t)(bg0 + bloc0 + l15) * T_SEQ + t) * 512 + ks * 32 + 8 * l4);
                #pragma unroll
                for (int ks = 0; ks < 16; ks++) {
                    const int ko = ks * 32 + 8 * l4;
                    const unsigned short* wb = Wcat1 + (size_t)j * 1024 + 512 + ko;
                    bf16x8 B0 = *(const bf16x8*)(wb);
                    bf16x8 B1 = *(const bf16x8*)(wb + 512 * 1024);
                    bf16x8 B2 = *(const bf16x8*)(wb + 1024 * 1024);
                    a0 = __builtin_amdgcn_mfma_f32_16x16x32_bf16(Areg[ks], B0, a0, 0, 0, 0);
                    a1 = __builtin_amdgcn_mfma_f32_16x16x32_bf16(Areg[ks], B1, a1, 0, 0, 0);
                    a3 = __builtin_amdgcn_mfma_f32_16x16x32_bf16(Areg[ks], B2, a3, 0, 0, 0);
                }
            }
            #pragma unroll
            for (int rr = 0; rr < 4; rr++) {
                int b = bg0 + bloc0 + 4 * l4 + rr;
                float r = sigm_fast(a0[rr] + br_);
                float z = sigm_fast(a1[rr] + bz_);
                float n = tanh_fast(a3[rr] + bnx_ + r * (a2[rr] + bn_));
                float h = (1.f - z) * n + z * carry[rr];
                carry[rr] = h;
                out1[((size_t)b * T_SEQ + t) * 512 + j] = f2bf(h);
            }
            asm volatile("s_waitcnt vmcnt(0)" ::: "memory");
            __syncthreads();
            if (tid == 0)
                __hip_atomic_store(myf, t, __ATOMIC_RELAXED, __HIP_MEMORY_SCOPE_AGENT);
        }
    }
}

// ---------------------------------------------------------------------------
// z partials (bf16 out reader): 960 blocks = (t, half, c-quarter).
// ---------------------------------------------------------------------------
__global__ __launch_bounds__(256) void zpart_kernel(
    const unsigned short* __restrict__ out, const float* __restrict__ Gw,
    float* __restrict__ zp)
{
    __shared__ float Os[128][33];
    __shared__ float Gs[128][33];
    int bk = blockIdx.x;
    int t = bk >> 3, half = (bk >> 2) & 1, cq = bk & 3;
    int tid = threadIdx.x;
    int tx = tid & 15, ty = tid >> 4;
    float acc[8][8] = {};
    int cbase = cq * 128;
    for (int c0 = cbase; c0 < cbase + 128; c0 += 32) {
        #pragma unroll
        for (int i = 0; i < 16; i++) {
            int e = tid + i * 256;
            int row = e >> 5, col = e & 31;
            Os[row][col] = bf2f(out[((size_t)(row + half * 128) * T_SEQ + t) * 512 + c0 + col]);
            float v = 0.f;
            if (row < 120)
                v = Gw[(size_t)row * KGATE + (size_t)t * 1024 + half * 512 + c0 + col];
            Gs[row][col] = v;
        }
        __syncthreads();
        #pragma unroll
        for (int kk = 0; kk < 32; kk++) {
            float a[8], g[8];
            #pragma unroll
            for (int i = 0; i < 8; i++) a[i] = Os[ty + i * 16][kk];
            #pragma unroll
            for (int j = 0; j < 8; j++) g[j] = Gs[tx + j * 16][kk];
            #pragma unroll
            for (int i = 0; i < 8; i++)
                #pragma unroll
                for (int j = 0; j < 8; j++) acc[i][j] += a[i] * g[j];
        }
        __syncthreads();
    }
    float* zb = zp + (size_t)bk * (128 * 120);
    #pragma unroll
    for (int i = 0; i < 8; i++) {
        int ii = ty + i * 16;
        #pragma unroll
        for (int j = 0; j < 8; j++) {
            int r = tx + j * 16;
            if (r < 120) zb[ii * 120 + r] = acc[i][j];
        }
    }
}

// 8 independent accumulators -> 8 outstanding loads/thread (BW-bound)
__global__ void zreduce(const float* __restrict__ zp,
                        const float* __restrict__ gate_b_l,
                        float* __restrict__ z)
{
    int idx = blockIdx.x * 256 + threadIdx.x;
    if (idx >= 128 * 120) return;
    const float* p = zp + idx;
    float s0 = 0, s1 = 0, s2 = 0, s3 = 0, s4 = 0, s5 = 0, s6 = 0, s7 = 0;
    for (int c = 0; c < 960; c += 8) {
        s0 += p[(size_t)(c + 0) * 15360];
        s1 += p[(size_t)(c + 1) * 15360];
        s2 += p[(size_t)(c + 2) * 15360];
        s3 += p[(size_t)(c + 3) * 15360];
        s4 += p[(size_t)(c + 4) * 15360];
        s5 += p[(size_t)(c + 5) * 15360];
        s6 += p[(size_t)(c + 6) * 15360];
        s7 += p[(size_t)(c + 7) * 15360];
    }
    z[idx] = ((s0 + s1) + (s2 + s3)) + ((s4 + s5) + (s6 + s7)) + gate_b_l[idx % 120];
}

// ---------------------------------------------------------------------------
// Fused per-column BN + sigmoid + batch-mean + softmax. 1 block, 512 thr.
// Wave w handles column r = c0+w; all reductions wave-local (no divergent
// barriers). Then wave 0 does the 120-way softmax alone.
// ---------------------------------------------------------------------------
__global__ __launch_bounds__(512) void bnsoft(
    const float* __restrict__ z, const float* __restrict__ gamma,
    const float* __restrict__ beta, float* __restrict__ g_out,
    float* __restrict__ g_ws)
{
    __shared__ float wm_s[128];
    const int w = threadIdx.x >> 6, lane = threadIdx.x & 63;
    for (int c0 = 0; c0 < 120; c0 += 8) {
        int r = c0 + w;
        if (r < 120) {
            float v0 = z[lane * 120 + r];
            float v1 = z[(lane + 64) * 120 + r];
            float s = v0 + v1;
            for (int o = 32; o > 0; o >>= 1) s += __shfl_down(s, o);
            float m = __shfl(s, 0) * (1.f / 128.f);
            float d = (v0 - m) * (v0 - m) + (v1 - m) * (v1 - m);
            for (int o = 32; o > 0; o >>= 1) d += __shfl_down(d, o);
            float var = __shfl(d, 0) * (1.f / 128.f);
            float inv = 1.f / sqrtf(var + 1e-5f);
            float g = gamma[r], bt = beta[r];
            float w0 = 1.f / (1.f + expf(-(g * (v0 - m) * inv + bt)));
            float w1 = 1.f / (1.f + expf(-(g * (v1 - m) * inv + bt)));
            float ws = w0 + w1;
            for (int o = 32; o > 0; o >>= 1) ws += __shfl_down(ws, o);
            if (lane == 0) wm_s[r] = ws * (1.f / 128.f);
        }
    }
    __syncthreads();
    if (w == 0) {                                    // softmax over 120, wave 0
        float v0 = (lane < 120) ? wm_s[lane] : -1e30f;
        float v1 = (lane + 64 < 120) ? wm_s[lane + 64] : -1e30f;
        float mx = fmaxf(v0, v1);
        for (int o = 32; o > 0; o >>= 1) mx = fmaxf(mx, __shfl_down(mx, o));
        mx = __shfl(mx, 0);
        float e0 = (lane < 120) ? expf(v0 - mx) : 0.f;
        float e1 = (lane + 64 < 120) ? expf(v1 - mx) : 0.f;
        float se = e0 + e1;
        for (int o = 32; o > 0; o >>= 1) se += __shfl_down(se, o);
        se = __shfl(se, 0);
        if (lane < 120)      { float g = e0 / se; g_out[lane] = g;      g_ws[lane] = g; }
        if (lane + 64 < 120) { float g = e1 / se; g_out[lane + 64] = g; g_ws[lane + 64] = g; }
    }
}

__global__ void halfmeans(const unsigned short* __restrict__ out,
                          float* __restrict__ ms, float* __restrict__ mt)
{
    int idx = blockIdx.x * 256 + threadIdx.x;
    int half = idx >= TS;
    int tc = idx - half * TS;
    const unsigned short* base = out + (size_t)(half * 128) * TS + tc;
    float s = 0.f;
    for (int i = 0; i < 128; i++) s += bf2f(base[(size_t)i * TS]);
    s *= (1.f / 128.f);
    if (half) mt[tc] = s; else ms[tc] = s;
}

__global__ __launch_bounds__(512) void transfer_part(
    const float* __restrict__ ms, const float* __restrict__ mt,
    const float* __restrict__ gw, const int* __restrict__ lenw,
    float* __restrict__ part)
{
    int t = blockIdx.x, c = threadIdx.x;
    int lw = lenw[0];
    int j0 = t - lw; if (j0 < 0) j0 = 0;
    int j1 = t + lw; if (j1 > 119) j1 = 119;
    float m_c = ms[(size_t)t * 512 + c];
    float acc = 0.f;
    for (int j = j0; j <= j1; j++) {
        float d = m_c - mt[(size_t)j * 512 + c];
        acc += d * d;
    }
    for (int o = 32; o > 0; o >>= 1) acc += __shfl_down(acc, o);
    __shared__ float sh[8];
    if ((c & 63) == 0) sh[c >> 6] = acc;
    __syncthreads();
    if (c == 0) {
        float s = 0.f;
        #pragma unroll
        for (int k = 0; k < 8; k++) s += sh[k];
        part[t] = gw[t] * s;
    }
}

__global__ __launch_bounds__(256) void yhat_kernel(
    const unsigned short* __restrict__ out1, const float* __restrict__ y,
    const float* __restrict__ fcW, const float* __restrict__ fcb,
    int dsl, float* __restrict__ dout, float* __restrict__ lp_rows)
{
    int wid = blockIdx.x * 4 + (threadIdx.x >> 6);   // 0..dsl*256-1
    int lane = threadIdx.x & 63;
    int tt = wid >> 8, b = wid & 255;
    int t = T_SEQ - dsl + tt;
    const unsigned short* row = out1 + ((size_t)b * T_SEQ + t) * 512;
    float s = 0.f;
    #pragma unroll
    for (int k = 0; k < 8; k++) s += bf2f(row[lane + 64 * k]) * fcW[lane + 64 * k];
    for (int o = 32; o > 0; o >>= 1) s += __shfl_down(s, o);
    if (lane == 0) {
        float loc = s + fcb[0];
        float sp = fmaxf(loc, 0.f) + log1pf(expf(-fabsf(loc)));
        float scale = sp + 1e-6f;
        dout[2 + tt * 256 + b] = loc;
        dout[2 + dsl * 256 + tt * 256 + b] = scale;
        float yt = y[(size_t)t * 256 + b];
        float u = (yt - loc) / scale;
        lp_rows[wid] = -0.5f * u * u - logf(scale) - 0.91893853320467274f;
    }
}

__global__ __launch_bounds__(64) void finalize(
    const float* __restrict__ lp_rows, const float* __restrict__ part0,
    const float* __restrict__ part1, float* __restrict__ dout, int n_lp)
{
    int i = threadIdx.x;
    float s = 0.f;
    for (int k = i; k < n_lp; k += 64) s += lp_rows[k];
    for (int o = 32; o > 0; o >>= 1) s += __shfl_down(s, o);
    float tr = 0.f;
    for (int k = i; k < 120; k += 64) tr += part0[k] + part1[k];
    for (int o = 32; o > 0; o >>= 1) tr += __shfl_down(tr, o);
    if (i == 0) {
        float ly = -s / (float)n_lp;
        dout[1] = ly;
        dout[0] = ly + tr;
    }
}

// ---------------------------------------------------------------------------
extern "C" void kernel_launch(void* const* d_in, const int* in_sizes, int n_in,
                              void* d_out, int out_size, void* d_ws, size_t ws_size,
                              hipStream_t stream)
{
    const float* X_cov  = (const float*)d_in[1];
    const float* X_lag  = (const float*)d_in[2];
    const float* y      = (const float*)d_in[3];
    const int*   lenw   = (const int*)d_in[5];
    const float* W_ih0  = (const float*)d_in[6];
    const float* W_hh0  = (const float*)d_in[7];
    const float* b_ih0  = (const float*)d_in[8];
    const float* b_hh0  = (const float*)d_in[9];
    const float* W_ih1  = (const float*)d_in[10];
    const float* W_hh1  = (const float*)d_in[11];
    const float* b_ih1  = (const float*)d_in[12];
    const float* b_hh1  = (const float*)d_in[13];
    const float* gate_W = (const float*)d_in[14];
    const float* gate_b = (const float*)d_in[15];
    const float* bn_g   = (const float*)d_in[16];
    const float* bn_b   = (const float*)d_in[17];
    const float* fc_W   = (const float*)d_in[18];
    const float* fc_b   = (const float*)d_in[19];
    float* dout = (float*)d_out;
    float* ws   = (float*)d_ws;

    // workspace layout (float offsets)
    unsigned short* out0  = (unsigned short*)(ws);                // 15,728,640 ush
    unsigned short* out1  = (unsigned short*)(ws + 7864320);      // 15,728,640 ush
    unsigned short* Whh0bf  = (unsigned short*)(ws + 15728640);   // 786,432 ush
    unsigned short* Wcat1bf = (unsigned short*)(ws + 16121856);   // 1,572,864 ush
    float* zp      = ws + 16908288;               // 14,745,600
    float* zmat    = ws + 31653888;               // 15,360
    float* gw_ws   = ws + 31669368;               // 240
    float* msb     = ws + 31669608;               // 61,440
    float* mtb     = ws + 31731048;               // 61,440
    float* part    = ws + 31792488;               // 240
    float* bcomb0  = ws + 31792728;               // 1536
    float* bc1     = ws + 31794264;               // 1536
    int*   flags   = (int*)(ws + 31795800);       // 4096 ints
    int*   rolecnt = (int*)(ws + 31799896);       // 128 ints
    float* lp_rows = ws + 31800024;               // 6144

    int dsl = (out_size - 2 - 2 * T_SEQ) / (2 * BATCH);   // = 24

    prep<<<dim3(9240), 256, 0, stream>>>(W_hh0, W_hh1, W_ih1,
                                         b_ih0, b_hh0, b_ih1, b_hh1,
                                         Whh0bf, Wcat1bf, bcomb0, bc1,
                                         flags, rolecnt);

    gru_xcd<<<dim3(320), 256, 0, stream>>>(X_lag, X_cov, W_ih0,
                                           Whh0bf, Wcat1bf,
                                           b_hh0, bcomb0, bc1, b_hh1,
                                           out0, out1, flags, rolecnt);

    for (int l = 0; l < 2; l++) {
        const unsigned short* o = l ? out1 : out0;
        zpart_kernel<<<960, 256, 0, stream>>>(o, gate_W + (size_t)l * 120 * KGATE, zp);
        zreduce<<<60, 256, 0, stream>>>(zp, gate_b + l * 120, zmat);
        bnsoft<<<1, 512, 0, stream>>>(zmat, bn_g + l * 120, bn_b + l * 120,
                                      dout + 2 + 2 * dsl * 256 + l * 120,
                                      gw_ws + l * 120);
        halfmeans<<<480, 256, 0, stream>>>(o, msb, mtb);
        transfer_part<<<120, 512, 0, stream>>>(msb, mtb, gw_ws + l * 120, lenw,
                                               part + l * 120);
    }

    yhat_kernel<<<dsl * 64, 256, 0, stream>>>(out1, y, fc_W, fc_b, dsl, dout, lp_rows);
    finalize<<<1, 64, 0, stream>>>(lp_rows, part, part + 120, dout, dsl * 256);
}

// Round 16
// 1756.764 us; speedup vs baseline: 1.0565x; 1.0565x over previous
//
#include <hip/hip_runtime.h>
#include <math.h>

#define T_SEQ 120
#define BATCH 256
#define HID   512
#define G3    1536            // 3*HID
#define TS    (T_SEQ*HID)     // 61440
#define KGATE 122880          // T_SEQ*2*HID
#define FSTRIDE 16            // flag stride (ints) -> one flag per 64B line

typedef __attribute__((ext_vector_type(8))) short bf16x8;
typedef __attribute__((ext_vector_type(4))) float f32x4;

__device__ __forceinline__ unsigned short f2bf(float f) {
    union { float f; unsigned u; } x; x.f = f;
    unsigned r = x.u + 0x7fffu + ((x.u >> 16) & 1u);   // RNE
    return (unsigned short)(r >> 16);
}
__device__ __forceinline__ float bf2f(unsigned short u) {
    union { unsigned u; float f; } x; x.u = ((unsigned)u) << 16; return x.f;
}
__device__ __forceinline__ float sigm_fast(float x) {
    return 1.f / (1.f + __expf(-x));
}
__device__ __forceinline__ float tanh_fast(float x) {
    float e = __expf(2.f * x);
    return 1.f - 2.f / (e + 1.f);
}

// ---------------------------------------------------------------------------
// One prep kernel: weight casts + bias combos + flag/rolecnt init. [r15 ok]
// ---------------------------------------------------------------------------
#define P_T1 786432
#define P_T2 (P_T1 + 1572864)
#define P_T3 (P_T2 + 1536)
#define P_T4 (P_T3 + 4224)

__global__ void prep(const float* __restrict__ Whh0f, const float* __restrict__ Whh1f,
                     const float* __restrict__ Wih1f,
                     const float* __restrict__ bih0, const float* __restrict__ bhh0,
                     const float* __restrict__ bih1, const float* __restrict__ bhh1,
                     unsigned short* __restrict__ Whh0bf,
                     unsigned short* __restrict__ Wcat1bf,
                     float* __restrict__ bcomb0, float* __restrict__ bc1,
                     int* __restrict__ flags, int* __restrict__ rolecnt)
{
    int idx = blockIdx.x * 256 + threadIdx.x;
    if (idx < P_T1) {
        Whh0bf[idx] = f2bf(Whh0f[idx]);
    } else if (idx < P_T2) {
        int i = idx - P_T1;
        int row = i >> 10, c = i & 1023;
        float v = (c < 512) ? Whh1f[row * 512 + c] : Wih1f[row * 512 + (c - 512)];
        Wcat1bf[i] = f2bf(v);
    } else if (idx < P_T3) {
        int n = idx - P_T2;
        bcomb0[n] = bih0[n] + (n < 1024 ? bhh0[n] : 0.f);
        bc1[n]    = bih1[n] + (n < 1024 ? bhh1[n] : 0.f);
    } else if (idx < P_T4) {
        int k = idx - P_T3;
        if (k < 4096) flags[k] = -1;
        else          rolecnt[k - 4096] = 0;
    }
}

// ---------------------------------------------------------------------------
// XCD-partitioned persistent recurrence: r14/r15 PROVEN kernel, unchanged.
// ~13.6us/step = measured mechanism-independent inter-CU visibility floor
// (7 protocol variants, r5-r14, all within 13.6-15.5 us/step).
// ---------------------------------------------------------------------------
__device__ __forceinline__ bool wait16(const int* __restrict__ fb, int thr, int lane)
{
    const int* ap = fb + (lane & 15) * FSTRIDE;
    float x0 = (float)lane, x1 = x0 + 1.f, x2 = x0 + 2.f, x3 = x0 + 3.f;
    for (int it = 0; it < 300000; ++it) {
        int v = __hip_atomic_load(ap, __ATOMIC_RELAXED, __HIP_MEMORY_SCOPE_AGENT);
        if (__all(v >= thr)) {
            asm volatile("" :: "v"(x0), "v"(x1), "v"(x2), "v"(x3));
            return true;
        }
        #pragma unroll
        for (int q = 0; q < 12; q++) {
            x0 = __builtin_fmaf(x0, 1.000001f, 1e-7f);
            x1 = __builtin_fmaf(x1, 1.000001f, 1e-7f);
            x2 = __builtin_fmaf(x2, 1.000001f, 1e-7f);
            x3 = __builtin_fmaf(x3, 1.000001f, 1e-7f);
        }
    }
    asm volatile("" :: "v"(x0), "v"(x1), "v"(x2), "v"(x3));
    return false;   // hang guard: terminate (wrong) rather than hang
}

__global__ __launch_bounds__(256) void gru_xcd(
    const float* __restrict__ X_lag,                 // [120][256][32] f32
    const float* __restrict__ X_cov,                 // [120][256][32] f32
    const float* __restrict__ Wih0,                  // [1536][64] f32
    const unsigned short* __restrict__ Whh0,         // [1536][512] bf16
    const unsigned short* __restrict__ Wcat1,        // [1536][1024] bf16
    const float* __restrict__ bhh0,
    const float* __restrict__ bcomb0,                // b_ih0 + b_hh0(r,z)
    const float* __restrict__ bc1,
    const float* __restrict__ bhh1,
    unsigned short* __restrict__ out0,               // [256][120][512] bf16
    unsigned short* __restrict__ out1,               // [256][120][512] bf16
    int* __restrict__ flags,                         // [2][8][16] x FSTRIDE
    int* __restrict__ rolecnt)                       // [8] (x16 pad)
{
    __shared__ unsigned short wlds[96 * 520];        // ~97.5 KiB (hh weights)
    __shared__ float wih[96 * 68];                   // ~25.5 KiB (L0 ih weights)
    __shared__ int role_s;

    int xcd;
    asm("s_getreg_b32 %0, hwreg(20, 0, 32)" : "=s"(xcd));   // HW_REG_XCC_ID
    xcd &= 7;
    if (threadIdx.x == 0) role_s = atomicAdd(&rolecnt[xcd * 16], 1);
    __syncthreads();
    const int role = role_s;
    if (role >= 32) return;

    const int layer = role >> 4;
    const int jb    = role & 15;
    const int j0    = jb * 32;
    const int tid   = threadIdx.x;
    const int w     = tid >> 6, lane = tid & 63;
    const int l15   = lane & 15, l4 = lane >> 4;
    const int jt    = w & 1, bt = w >> 1;
    const int jloc  = jt * 16 + l15;                 // 0..31
    const int j     = j0 + jloc;
    const int bloc0 = bt * 16;                       // 0 or 16
    const int bg0   = xcd * 32;                      // global batch base

    // stage hh-part weights (96 rows x 512) into LDS, padded stride 520
    {
        const unsigned short* Wsrc = layer ? Wcat1 : Whh0;
        const int wstr = layer ? 1024 : 512;
        for (int c = tid; c < 96 * 64; c += 256) {
            int lr = c >> 6, ck = c & 63;
            int grow = (lr >> 5) * 512 + j0 + (lr & 31);
            bf16x8 v = *(const bf16x8*)(Wsrc + (size_t)grow * wstr + ck * 8);
            *(bf16x8*)&wlds[lr * 520 + ck * 8] = v;
        }
    }
    // L0 only: stage ih weights (96 rows x 64 f32), padded stride 68
    if (!layer) {
        for (int c = tid; c < 96 * 16; c += 256) {
            int row = c >> 4, q = c & 15;
            int grow = (row >> 5) * 512 + j0 + (row & 31);
            float4 v = *(const float4*)(Wih0 + (size_t)grow * 64 + q * 4);
            *(float4*)&wih[row * 68 + q * 4] = v;
        }
    }
    float bn_, br_ = 0.f, bz_ = 0.f, bnx_ = 0.f;
    if (layer) { br_ = bc1[j]; bz_ = bc1[512 + j]; bnx_ = bc1[1024 + j]; bn_ = bhh1[1024 + j]; }
    else       { br_ = bcomb0[j]; bz_ = bcomb0[512 + j]; bnx_ = bcomb0[1024 + j]; bn_ = bhh0[1024 + j]; }
    float carry[4] = {0.f, 0.f, 0.f, 0.f};

    const int* f0b = flags + (0 * 8 + xcd) * 16 * FSTRIDE;
    const int* f1b = flags + (1 * 8 + xcd) * 16 * FSTRIDE;
    int* myf = flags + ((layer * 8 + xcd) * 16 + jb) * FSTRIDE;
    __syncthreads();                                 // weights staged

    if (!layer) {
        // ============================ layer 0 ============================
        for (int t = 0; t < T_SEQ; t++) {
            // fused gx = x_t @ Wih0^T  (f32, no h dependency -> before wait)
            float dr[4] = {}, dz[4] = {}, dn[4] = {};
            #pragma unroll
            for (int kc = 0; kc < 16; kc++) {
                float4 w0 = *(const float4*)&wih[(0 * 32 + jloc) * 68 + kc * 4];
                float4 w1 = *(const float4*)&wih[(1 * 32 + jloc) * 68 + kc * 4];
                float4 w2 = *(const float4*)&wih[(2 * 32 + jloc) * 68 + kc * 4];
                #pragma unroll
                for (int rr = 0; rr < 4; rr++) {
                    int b = bg0 + bloc0 + 4 * l4 + rr;
                    const float* xr = (kc < 8)
                        ? X_lag + ((size_t)t * 256 + b) * 32 + kc * 4
                        : X_cov + ((size_t)t * 256 + b) * 32 + (kc - 8) * 4;
                    float4 xv = *(const float4*)xr;
                    dr[rr] += xv.x * w0.x + xv.y * w0.y + xv.z * w0.z + xv.w * w0.w;
                    dz[rr] += xv.x * w1.x + xv.y * w1.y + xv.z * w1.z + xv.w * w1.w;
                    dn[rr] += xv.x * w2.x + xv.y * w2.y + xv.z * w2.z + xv.w * w2.w;
                }
            }

            if (!wait16(f0b, t - 1, lane)) break;    // all h0(t-1) published

            f32x4 a0 = {0,0,0,0}, a1 = {0,0,0,0}, a2 = {0,0,0,0};
            if (t > 0) {
                bf16x8 Areg[16];
                #pragma unroll
                for (int ks = 0; ks < 16; ks++)
                    Areg[ks] = *(const bf16x8*)(out0 + ((size_t)(bg0 + bloc0 + l15) * T_SEQ + (t - 1)) * 512 + ks * 32 + 8 * l4);
                #pragma unroll
                for (int ks = 0; ks < 16; ks++) {
                    const int ko = ks * 32 + 8 * l4;
                    bf16x8 B0 = *(const bf16x8*)&wlds[(0 * 32 + jloc) * 520 + ko];
                    bf16x8 B1 = *(const bf16x8*)&wlds[(1 * 32 + jloc) * 520 + ko];
                    bf16x8 B2 = *(const bf16x8*)&wlds[(2 * 32 + jloc) * 520 + ko];
                    a0 = __builtin_amdgcn_mfma_f32_16x16x32_bf16(Areg[ks], B0, a0, 0, 0, 0);
                    a1 = __builtin_amdgcn_mfma_f32_16x16x32_bf16(Areg[ks], B1, a1, 0, 0, 0);
                    a2 = __builtin_amdgcn_mfma_f32_16x16x32_bf16(Areg[ks], B2, a2, 0, 0, 0);
                }
            }
            #pragma unroll
            for (int rr = 0; rr < 4; rr++) {
                int b = bg0 + bloc0 + 4 * l4 + rr;
                float r = sigm_fast(dr[rr] + br_ + a0[rr]);
                float z = sigm_fast(dz[rr] + bz_ + a1[rr]);
                float n = tanh_fast(dn[rr] + bnx_ + r * (a2[rr] + bn_));
                float h = (1.f - z) * n + z * carry[rr];
                carry[rr] = h;
                out0[((size_t)b * T_SEQ + t) * 512 + j] = f2bf(h);
            }
            asm volatile("s_waitcnt vmcnt(0)" ::: "memory");  // stores in L2
            __syncthreads();
            if (tid == 0)
                __hip_atomic_store(myf, t, __ATOMIC_RELAXED, __HIP_MEMORY_SCOPE_AGENT);
        }
    } else {
        // ============================ layer 1 ============================
        for (int t = 0; t < T_SEQ; t++) {
            f32x4 a0 = {0,0,0,0}, a1 = {0,0,0,0}, a2 = {0,0,0,0}, a3 = {0,0,0,0};
            // hh-part first: only needs own-layer flags >= t-1
            if (!wait16(f1b, t - 1, lane)) break;
            if (t > 0) {
                bf16x8 Areg[16];
                #pragma unroll
                for (int ks = 0; ks < 16; ks++)
                    Areg[ks] = *(const bf16x8*)(out1 + ((size_t)(bg0 + bloc0 + l15) * T_SEQ + (t - 1)) * 512 + ks * 32 + 8 * l4);
                #pragma unroll
                for (int ks = 0; ks < 16; ks++) {
                    const int ko = ks * 32 + 8 * l4;
                    bf16x8 B0 = *(const bf16x8*)&wlds[(0 * 32 + jloc) * 520 + ko];
                    bf16x8 B1 = *(const bf16x8*)&wlds[(1 * 32 + jloc) * 520 + ko];
                    bf16x8 B2 = *(const bf16x8*)&wlds[(2 * 32 + jloc) * 520 + ko];
                    a0 = __builtin_amdgcn_mfma_f32_16x16x32_bf16(Areg[ks], B0, a0, 0, 0, 0);
                    a1 = __builtin_amdgcn_mfma_f32_16x16x32_bf16(Areg[ks], B1, a1, 0, 0, 0);
                    a2 = __builtin_amdgcn_mfma_f32_16x16x32_bf16(Areg[ks], B2, a2, 0, 0, 0);
                }
            }
            // x-part: needs layer0 flags >= t
            if (!wait16(f0b, t, lane)) break;
            {
                bf16x8 Areg[16];
                #pragma unroll
                for (int ks = 0; ks < 16; ks++)
                    Areg[ks] = *(const bf16x8*)(out0 + ((size_t)(bg0 + bloc0 + l15) * T_SEQ + t) * 512 + ks * 32 + 8 * l4);
                #pragma unroll
                for (int ks = 0; ks < 16; ks++) {
                    const int ko = ks * 32 + 8 * l4;
                    const unsigned short* wb = Wcat1 + (size_t)j * 1024 + 512 + ko;
                    bf16x8 B0 = *(const bf16x8*)(wb);
                    bf16x8 B1 = *(const bf16x8*)(wb + 512 * 1024);
                    bf16x8 B2 = *(const bf16x8*)(wb + 1024 * 1024);
                    a0 = __builtin_amdgcn_mfma_f32_16x16x32_bf16(Areg[ks], B0, a0, 0, 0, 0);
                    a1 = __builtin_amdgcn_mfma_f32_16x16x32_bf16(Areg[ks], B1, a1, 0, 0, 0);
                    a3 = __builtin_amdgcn_mfma_f32_16x16x32_bf16(Areg[ks], B2, a3, 0, 0, 0);
                }
            }
            #pragma unroll
            for (int rr = 0; rr < 4; rr++) {
                int b = bg0 + bloc0 + 4 * l4 + rr;
                float r = sigm_fast(a0[rr] + br_);
                float z = sigm_fast(a1[rr] + bz_);
                float n = tanh_fast(a3[rr] + bnx_ + r * (a2[rr] + bn_));
                float h = (1.f - z) * n + z * carry[rr];
                carry[rr] = h;
                out1[((size_t)b * T_SEQ + t) * 512 + j] = f2bf(h);
            }
            asm volatile("s_waitcnt vmcnt(0)" ::: "memory");
            __syncthreads();
            if (tid == 0)
                __hip_atomic_store(myf, t, __ATOMIC_RELAXED, __HIP_MEMORY_SCOPE_AGENT);
        }
    }
}

// ---------------------------------------------------------------------------
// z partials, BOTH layers in one grid: 1920 blocks = (l, t, half, c-quarter).
// ---------------------------------------------------------------------------
__global__ __launch_bounds__(256) void zpart_kernel(
    const unsigned short* __restrict__ out0, const unsigned short* __restrict__ out1,
    const float* __restrict__ Gw,            // gate_W base: [2][120][KGATE]
    float* __restrict__ zp)                  // [2][960][15360]
{
    __shared__ float Os[128][33];
    __shared__ float Gs[128][33];
    int bk = blockIdx.x;
    int l = bk >= 960;
    int bk2 = bk - l * 960;
    int t = bk2 >> 3, half = (bk2 >> 2) & 1, cq = bk2 & 3;
    const unsigned short* out = l ? out1 : out0;
    const float* Gwl = Gw + (size_t)l * 120 * KGATE;
    int tid = threadIdx.x;
    int tx = tid & 15, ty = tid >> 4;
    float acc[8][8] = {};
    int cbase = cq * 128;
    for (int c0 = cbase; c0 < cbase + 128; c0 += 32) {
        #pragma unroll
        for (int i = 0; i < 16; i++) {
            int e = tid + i * 256;
            int row = e >> 5, col = e & 31;
            Os[row][col] = bf2f(out[((size_t)(row + half * 128) * T_SEQ + t) * 512 + c0 + col]);
            float v = 0.f;
            if (row < 120)
                v = Gwl[(size_t)row * KGATE + (size_t)t * 1024 + half * 512 + c0 + col];
            Gs[row][col] = v;
        }
        __syncthreads();
        #pragma unroll
        for (int kk = 0; kk < 32; kk++) {
            float a[8], g[8];
            #pragma unroll
            for (int i = 0; i < 8; i++) a[i] = Os[ty + i * 16][kk];
            #pragma unroll
            for (int j = 0; j < 8; j++) g[j] = Gs[tx + j * 16][kk];
            #pragma unroll
            for (int i = 0; i < 8; i++)
                #pragma unroll
                for (int j = 0; j < 8; j++) acc[i][j] += a[i] * g[j];
        }
        __syncthreads();
    }
    float* zb = zp + (size_t)bk * (128 * 120);
    #pragma unroll
    for (int i = 0; i < 8; i++) {
        int ii = ty + i * 16;
        #pragma unroll
        for (int j = 0; j < 8; j++) {
            int r = tx + j * 16;
            if (r < 120) zb[ii * 120 + r] = acc[i][j];
        }
    }
}

// both layers: idx < 2*15360; 8 outstanding loads/thread
__global__ void zreduce(const float* __restrict__ zp,
                        const float* __restrict__ gate_b,
                        float* __restrict__ z)
{
    int idx = blockIdx.x * 256 + threadIdx.x;
    if (idx >= 2 * 15360) return;
    int l = idx / 15360, e = idx - l * 15360;
    const float* p = zp + (size_t)l * 960 * 15360 + e;
    float s0 = 0, s1 = 0, s2 = 0, s3 = 0, s4 = 0, s5 = 0, s6 = 0, s7 = 0;
    for (int c = 0; c < 960; c += 8) {
        s0 += p[(size_t)(c + 0) * 15360];
        s1 += p[(size_t)(c + 1) * 15360];
        s2 += p[(size_t)(c + 2) * 15360];
        s3 += p[(size_t)(c + 3) * 15360];
        s4 += p[(size_t)(c + 4) * 15360];
        s5 += p[(size_t)(c + 5) * 15360];
        s6 += p[(size_t)(c + 6) * 15360];
        s7 += p[(size_t)(c + 7) * 15360];
    }
    z[idx] = ((s0 + s1) + (s2 + s3)) + ((s4 + s5) + (s6 + s7))
             + gate_b[l * 120 + e % 120];
}

// ---------------------------------------------------------------------------
// Fused BN+sigmoid+mean+softmax, one block per layer (grid=2). [r15 math]
// ---------------------------------------------------------------------------
__global__ __launch_bounds__(512) void bnsoft(
    const float* __restrict__ zmat, const float* __restrict__ bn_g,
    const float* __restrict__ bn_b, float* __restrict__ dout_g,
    float* __restrict__ gw_ws)
{
    __shared__ float wm_s[128];
    const int l = blockIdx.x;
    const float* z = zmat + l * 15360;
    const float* gamma = bn_g + l * 120;
    const float* beta  = bn_b + l * 120;
    float* g_out = dout_g + l * 120;
    float* g_ws  = gw_ws + l * 120;
    const int w = threadIdx.x >> 6, lane = threadIdx.x & 63;
    for (int c0 = 0; c0 < 120; c0 += 8) {
        int r = c0 + w;
        if (r < 120) {
            float v0 = z[lane * 120 + r];
            float v1 = z[(lane + 64) * 120 + r];
            float s = v0 + v1;
            for (int o = 32; o > 0; o >>= 1) s += __shfl_down(s, o);
            float m = __shfl(s, 0) * (1.f / 128.f);
            float d = (v0 - m) * (v0 - m) + (v1 - m) * (v1 - m);
            for (int o = 32; o > 0; o >>= 1) d += __shfl_down(d, o);
            float var = __shfl(d, 0) * (1.f / 128.f);
            float inv = 1.f / sqrtf(var + 1e-5f);
            float g = gamma[r], bt = beta[r];
            float w0 = 1.f / (1.f + expf(-(g * (v0 - m) * inv + bt)));
            float w1 = 1.f / (1.f + expf(-(g * (v1 - m) * inv + bt)));
            float ws = w0 + w1;
            for (int o = 32; o > 0; o >>= 1) ws += __shfl_down(ws, o);
            if (lane == 0) wm_s[r] = ws * (1.f / 128.f);
        }
    }
    __syncthreads();
    if (w == 0) {
        float v0 = (lane < 120) ? wm_s[lane] : -1e30f;
        float v1 = (lane + 64 < 120) ? wm_s[lane + 64] : -1e30f;
        float mx = fmaxf(v0, v1);
        for (int o = 32; o > 0; o >>= 1) mx = fmaxf(mx, __shfl_down(mx, o));
        mx = __shfl(mx, 0);
        float e0 = (lane < 120) ? expf(v0 - mx) : 0.f;
        float e1 = (lane + 64 < 120) ? expf(v1 - mx) : 0.f;
        float se = e0 + e1;
        for (int o = 32; o > 0; o >>= 1) se += __shfl_down(se, o);
        se = __shfl(se, 0);
        if (lane < 120)      { float g = e0 / se; g_out[lane] = g;      g_ws[lane] = g; }
        if (lane + 64 < 120) { float g = e1 / se; g_out[lane + 64] = g; g_ws[lane + 64] = g; }
    }
}

// both layers: idx < 2*2*TS; ms/mt are [2][61440]
__global__ void halfmeans(const unsigned short* __restrict__ out0,
                          const unsigned short* __restrict__ out1,
                          float* __restrict__ ms, float* __restrict__ mt)
{
    int idx = blockIdx.x * 256 + threadIdx.x;      // < 245760
    int l = idx / (2 * TS);
    int rem = idx - l * (2 * TS);
    int half = rem >= TS;
    int tc = rem - half * TS;
    const unsigned short* out = l ? out1 : out0;
    const unsigned short* base = out + (size_t)(half * 128) * TS + tc;
    float s = 0.f;
    for (int i = 0; i < 128; i++) s += bf2f(base[(size_t)i * TS]);
    s *= (1.f / 128.f);
    if (half) mt[l * TS + tc] = s; else ms[l * TS + tc] = s;
}

// both layers: 240 blocks = (l, t)
__global__ __launch_bounds__(512) void transfer_part(
    const float* __restrict__ ms, const float* __restrict__ mt,
    const float* __restrict__ gw_ws, const int* __restrict__ lenw,
    float* __restrict__ part)
{
    int l = blockIdx.x / 120, t = blockIdx.x - l * 120;
    int c = threadIdx.x;
    const float* msl = ms + l * TS;
    const float* mtl = mt + l * TS;
    int lw = lenw[0];
    int j0 = t - lw; if (j0 < 0) j0 = 0;
    int j1 = t + lw; if (j1 > 119) j1 = 119;
    float m_c = msl[(size_t)t * 512 + c];
    float acc = 0.f;
    for (int j = j0; j <= j1; j++) {
        float d = m_c - mtl[(size_t)j * 512 + c];
        acc += d * d;
    }
    for (int o = 32; o > 0; o >>= 1) acc += __shfl_down(acc, o);
    __shared__ float sh[8];
    if ((c & 63) == 0) sh[c >> 6] = acc;
    __syncthreads();
    if (c == 0) {
        float s = 0.f;
        #pragma unroll
        for (int k = 0; k < 8; k++) s += sh[k];
        part[blockIdx.x] = gw_ws[l * 120 + t] * s;
    }
}

__global__ __launch_bounds__(256) void yhat_kernel(
    const unsigned short* __restrict__ out1, const float* __restrict__ y,
    const float* __restrict__ fcW, const float* __restrict__ fcb,
    int dsl, float* __restrict__ dout, float* __restrict__ lp_rows)
{
    int wid = blockIdx.x * 4 + (threadIdx.x >> 6);   // 0..dsl*256-1
    int lane = threadIdx.x & 63;
    int tt = wid >> 8, b = wid & 255;
    int t = T_SEQ - dsl + tt;
    const unsigned short* row = out1 + ((size_t)b * T_SEQ + t) * 512;
    float s = 0.f;
    #pragma unroll
    for (int k = 0; k < 8; k++) s += bf2f(row[lane + 64 * k]) * fcW[lane + 64 * k];
    for (int o = 32; o > 0; o >>= 1) s += __shfl_down(s, o);
    if (lane == 0) {
        float loc = s + fcb[0];
        float sp = fmaxf(loc, 0.f) + log1pf(expf(-fabsf(loc)));
        float scale = sp + 1e-6f;
        dout[2 + tt * 256 + b] = loc;
        dout[2 + dsl * 256 + tt * 256 + b] = scale;
        float yt = y[(size_t)t * 256 + b];
        float u = (yt - loc) / scale;
        lp_rows[wid] = -0.5f * u * u - logf(scale) - 0.91893853320467274f;
    }
}

__global__ __launch_bounds__(64) void finalize(
    const float* __restrict__ lp_rows, const float* __restrict__ part,
    float* __restrict__ dout, int n_lp)
{
    int i = threadIdx.x;
    float s = 0.f;
    for (int k = i; k < n_lp; k += 64) s += lp_rows[k];
    for (int o = 32; o > 0; o >>= 1) s += __shfl_down(s, o);
    float tr = 0.f;
    for (int k = i; k < 240; k += 64) tr += part[k];
    for (int o = 32; o > 0; o >>= 1) tr += __shfl_down(tr, o);
    if (i == 0) {
        float ly = -s / (float)n_lp;
        dout[1] = ly;
        dout[0] = ly + tr;
    }
}

// ---------------------------------------------------------------------------
extern "C" void kernel_launch(void* const* d_in, const int* in_sizes, int n_in,
                              void* d_out, int out_size, void* d_ws, size_t ws_size,
                              hipStream_t stream)
{
    const float* X_cov  = (const float*)d_in[1];
    const float* X_lag  = (const float*)d_in[2];
    const float* y      = (const float*)d_in[3];
    const int*   lenw   = (const int*)d_in[5];
    const float* W_ih0  = (const float*)d_in[6];
    const float* W_hh0  = (const float*)d_in[7];
    const float* b_ih0  = (const float*)d_in[8];
    const float* b_hh0  = (const float*)d_in[9];
    const float* W_ih1  = (const float*)d_in[10];
    const float* W_hh1  = (const float*)d_in[11];
    const float* b_ih1  = (const float*)d_in[12];
    const float* b_hh1  = (const float*)d_in[13];
    const float* gate_W = (const float*)d_in[14];
    const float* gate_b = (const float*)d_in[15];
    const float* bn_g   = (const float*)d_in[16];
    const float* bn_b   = (const float*)d_in[17];
    const float* fc_W   = (const float*)d_in[18];
    const float* fc_b   = (const float*)d_in[19];
    float* dout = (float*)d_out;
    float* ws   = (float*)d_ws;

    // workspace layout (float offsets)
    unsigned short* out0  = (unsigned short*)(ws);                // [256][120][512]
    unsigned short* out1  = (unsigned short*)(ws + 7864320);
    unsigned short* Whh0bf  = (unsigned short*)(ws + 15728640);   // 786,432 ush
    unsigned short* Wcat1bf = (unsigned short*)(ws + 16121856);   // 1,572,864 ush
    float* zp      = ws + 16908288;               // 2*960*15360 = 29,491,200
    float* zmat    = ws + 46399488;               // 30,720
    float* gw_ws   = ws + 46430208;               // 240
    float* msb     = ws + 46430448;               // 2*61,440
    float* mtb     = ws + 46553328;               // 2*61,440
    float* part    = ws + 46676208;               // 240
    float* bcomb0  = ws + 46676448;               // 1536
    float* bc1     = ws + 46677984;               // 1536
    int*   flags   = (int*)(ws + 46679520);       // 4096 ints
    int*   rolecnt = (int*)(ws + 46683616);       // 128 ints
    float* lp_rows = ws + 46683744;               // 6144

    int dsl = (out_size - 2 - 2 * T_SEQ) / (2 * BATCH);   // = 24

    prep<<<dim3(9240), 256, 0, stream>>>(W_hh0, W_hh1, W_ih1,
                                         b_ih0, b_hh0, b_ih1, b_hh1,
                                         Whh0bf, Wcat1bf, bcomb0, bc1,
                                         flags, rolecnt);

    gru_xcd<<<dim3(320), 256, 0, stream>>>(X_lag, X_cov, W_ih0,
                                           Whh0bf, Wcat1bf,
                                           b_hh0, bcomb0, bc1, b_hh1,
                                           out0, out1, flags, rolecnt);

    zpart_kernel<<<1920, 256, 0, stream>>>(out0, out1, gate_W, zp);
    zreduce<<<120, 256, 0, stream>>>(zp, gate_b, zmat);
    bnsoft<<<2, 512, 0, stream>>>(zmat, bn_g, bn_b,
                                  dout + 2 + 2 * dsl * 256, gw_ws);
    halfmeans<<<960, 256, 0, stream>>>(out0, out1, msb, mtb);
    transfer_part<<<240, 512, 0, stream>>>(msb, mtb, gw_ws, lenw, part);

    yhat_kernel<<<dsl * 64, 256, 0, stream>>>(out1, y, fc_W, fc_b, dsl, dout, lp_rows);
    finalize<<<1, 64, 0, stream>>>(lp_rows, part, dout, dsl * 256);
}